// Round 9
// baseline (117.011 us; speedup 1.0000x reference)
//
#include <hip/hip_runtime.h>

namespace {

typedef __attribute__((ext_vector_type(4))) float f32x4;
typedef __attribute__((ext_vector_type(8))) short bf16x8;

constexpr int WFRAG_ELEMS = 24 * 8 * 64 * 8;          // 98304 bf16
constexpr int WFRAG_BYTES = WFRAG_ELEMS * 2;          // 196608
constexpr int BIAS_ELEMS  = 8 * 64 * 64;              // 32768 f32
constexpr size_t WS_NEEDED = (size_t)WFRAG_BYTES + (size_t)BIAS_ELEMS * 4;  // 327680

// LDS arena (bytes):
//  - XS [0..32768): x staged as MFMA A-fragments (dead after proj MFMAs)
//  - CB [0..24576): this head-group's 192 proj cols (4 heads Q+K), bf16,
//                   XOR-swizzled, 64 rows x 384B (overlays XS after it dies)
//  - PB [24576..40960): per-wave 4KB f32 store-bounce tiles (DISJOINT from CB)
constexpr int PB_OFF    = 24576;
constexpr int LDS_TOTAL = 40960;           // -> 4 blocks/CU (VGPR <= 128)

__device__ __forceinline__ unsigned short f2bf(float f) {
  unsigned u = __float_as_uint(f);
  u += 0x7fffu + ((u >> 16) & 1u);   // RNE
  return (unsigned short)(u >> 16);
}

// byte offset of CB[row][c] (bf16, c in [0,192)) with 16B-slot XOR swizzle
__device__ __forceinline__ int cb_addr(int row, int c) {
  const int slot = (c >> 3) ^ (row & 7);   // XOR flips low 3 bits: stays in 8-group
  return row * 384 + (slot << 4) + ((c & 7) << 1);
}

// bounce-tile slot: P[row16][ktq], 16B slot = (ktq ^ row16) & 15
__device__ __forceinline__ int pb_addr(int pbase, int row16, int ktq) {
  return pbase + row16 * 256 + (((ktq ^ row16) & 15) << 4);
}

__global__ void prep(const float* __restrict__ w_in,
                     const float* __restrict__ btab,
                     const int*   __restrict__ rpidx,
                     unsigned short* __restrict__ wfrag,
                     float* __restrict__ biasx) {
  const int t = blockIdx.x * 256 + threadIdx.x;
  if (t < WFRAG_ELEMS) {
    const int j    = t & 7;
    const int lane = (t >> 3) & 63;
    const int kk   = (t >> 9) & 7;
    const int nt   = t >> 12;
    const int k    = kk * 32 + (lane >> 4) * 8 + j;
    const int col  = nt * 16 + (lane & 15);
    wfrag[t] = f2bf(w_in[k * 384 + col]);
  } else if (t < WFRAG_ELEMS + BIAS_ELEMS) {
    const int o = t - WFRAG_ELEMS;
    const int j = o & 63, i = (o >> 6) & 63, h = o >> 12;
    biasx[o] = btab[rpidx[i * 64 + j] * 8 + h];
  }
}

template <bool USE_WS>
__global__ __launch_bounds__(256, 4)
void fused_mhaw(const float* __restrict__ x,
                const int*   __restrict__ reidx,
                const float* __restrict__ w_in,
                const float* __restrict__ b_in,
                const float* __restrict__ btab,
                const int*   __restrict__ rpidx,
                const unsigned short* __restrict__ wfrag,
                const float* __restrict__ biasx,
                float*       __restrict__ out) {
  extern __shared__ char lds[];
  unsigned short* xs = reinterpret_cast<unsigned short*>(lds);

  const int tid  = threadIdx.x;
  const int blk  = blockIdx.x;
  const int b    = blk >> 11;            // batch
  const int g    = (blk >> 10) & 1;      // head group (heads 4g..4g+3)
  const int win  = blk & 1023;
  const int wh   = win >> 5, ww = win & 31;
  const int wave = tid >> 6, lane = tid & 63;
  const int l15  = lane & 15, q = lane >> 4;
  const int pbase = PB_OFF + wave * 4096;

  // ---------------- stage gathered x rows as MFMA A-fragments --------------
  {
    const int srow = tid >> 2;       // token row this thread stages
    const int part = tid & 3;        // 32-float chunk within each K-half
    const int sm_t = srow >> 4, sr15 = srow & 15;
    const int swr  = sr15 ^ (part << 1);   // break 8-way write conflict
    const int tokv = reidx[(wh * 8 + (srow >> 3)) * 256 + ww * 8 + (srow & 7)];
    const float* xrow = x + ((size_t)b * 65536 + (size_t)tokv) * 256;
#pragma unroll
    for (int hf = 0; hf < 2; ++hf) {
      const float* src = xrow + hf * 128 + part * 32;
#pragma unroll
      for (int gg = 0; gg < 4; ++gg) {
        const float4 v0 = *reinterpret_cast<const float4*>(src + gg * 8);
        const float4 v1 = *reinterpret_cast<const float4*>(src + gg * 8 + 4);
        bf16x8 u;
        u[0] = (short)f2bf(v0.x); u[1] = (short)f2bf(v0.y);
        u[2] = (short)f2bf(v0.z); u[3] = (short)f2bf(v0.w);
        u[4] = (short)f2bf(v1.x); u[5] = (short)f2bf(v1.y);
        u[6] = (short)f2bf(v1.z); u[7] = (short)f2bf(v1.w);
        *reinterpret_cast<bf16x8*>(
            xs + ((sm_t * 8 + hf * 4 + part) * 64 + gg * 16 + swr) * 8) = u;
      }
    }
  }
  __syncthreads();

  // ------- projection (transposed): wave w computes local col-tiles 3w..3w+2
  // local tile t covers CB cols [16t,16t+16); global col-tile:
  //   t<6 -> Q tile 6g+t ; t>=6 -> K tile 12+6g+(t-6)
  f32x4 acc[3][4];
#pragma unroll
  for (int n = 0; n < 3; ++n)
#pragma unroll
    for (int m = 0; m < 4; ++m) acc[n][m] = (f32x4){0.f, 0.f, 0.f, 0.f};

#pragma unroll
  for (int kk = 0; kk < 8; ++kk) {
    const int rlane = q * 16 + (l15 ^ ((kk & 3) << 1));   // un-swizzle
    bf16x8 af[4];
#pragma unroll
    for (int m = 0; m < 4; ++m)
      af[m] = *reinterpret_cast<const bf16x8*>(xs + ((m * 8 + kk) * 64 + rlane) * 8);
#pragma unroll
    for (int n = 0; n < 3; ++n) {
      const int t  = 3 * wave + n;
      const int gt = (t < 6) ? (6 * g + t) : (12 + 6 * g + (t - 6));
      bf16x8 bfr;
      if (USE_WS) {
        bfr = *reinterpret_cast<const bf16x8*>(
            wfrag + (((size_t)gt * 8 + kk) * 64 + lane) * 8);
      } else {
        const int colg = gt * 16 + l15;
#pragma unroll
        for (int jj = 0; jj < 8; ++jj)
          bfr[jj] = (short)f2bf(w_in[(kk * 32 + q * 8 + jj) * 384 + colg]);
      }
#pragma unroll
      for (int m = 0; m < 4; ++m)
        acc[n][m] = __builtin_amdgcn_mfma_f32_16x16x32_bf16(bfr, af[m], acc[n][m], 0, 0, 0);
    }
  }
  __syncthreads();   // xs dead; CB overlays it

  // write CB (+bias), transposed acc -> vectorized ds_write_b64
#pragma unroll
  for (int n = 0; n < 3; ++n) {
    const int t  = 3 * wave + n;
    const int gt = (t < 6) ? (6 * g + t) : (12 + 6 * g + (t - 6));
    const int cl = t * 16 + q * 4;                 // local CB col base
    const float4 bv = *reinterpret_cast<const float4*>(b_in + gt * 16 + q * 4);
#pragma unroll
    for (int m = 0; m < 4; ++m) {
      ushort4 u;
      u.x = f2bf(acc[n][m][0] + bv.x);
      u.y = f2bf(acc[n][m][1] + bv.y);
      u.z = f2bf(acc[n][m][2] + bv.z);
      u.w = f2bf(acc[n][m][3] + bv.w);
      *reinterpret_cast<ushort4*>(lds + cb_addr(m * 16 + l15, cl)) = u;
    }
  }
  __syncthreads();

  // ---------------- head h = 4g + wave: K·Qᵀ + bias + softmax --------------
  // CB [0..24K) and PB [24K..40K) are disjoint: no further barriers needed.
  const bf16x8 vz = {0, 0, 0, 0, 0, 0, 0, 0};
  const f32x4 cz = {0.f, 0.f, 0.f, 0.f};
  const int h = 4 * g + wave;
  const size_t obase = (((size_t)h * 2 + b) * 1024 + win) * 4096;

  bf16x8 bk[4];
#pragma unroll
  for (int ai = 0; ai < 4; ++ai)
    bk[ai] = (lane < 48)
                 ? *reinterpret_cast<const bf16x8*>(
                       lds + cb_addr(ai * 16 + l15, 96 + 24 * wave + q * 8))
                 : vz;

#pragma unroll
  for (int bi = 0; bi < 4; ++bi) {
    const bf16x8 aq = (lane < 48)
                          ? *reinterpret_cast<const bf16x8*>(
                                lds + cb_addr(bi * 16 + l15, 24 * wave + q * 8))
                          : vz;

    // p[ai] = Sᵀ tile: rows kt = ai*16 + q*4 + r, col qt = bi*16 + l15
    f32x4 p[4];
#pragma unroll
    for (int ai = 0; ai < 4; ++ai)
      p[ai] = __builtin_amdgcn_mfma_f32_16x16x32_bf16(bk[ai], aq, cz, 0, 0, 0);

    const int qt = bi * 16 + l15;      // query row this lane owns
#pragma unroll
    for (int ai = 0; ai < 4; ++ai) {
      if (USE_WS) {
        const f32x4 bb = *reinterpret_cast<const f32x4*>(
            biasx + ((size_t)(h * 64 + qt)) * 64 + ai * 16 + q * 4);
        p[ai] += bb;
      } else {
#pragma unroll
        for (int r = 0; r < 4; ++r)
          p[ai][r] += btab[rpidx[qt * 64 + ai * 16 + q * 4 + r] * 8 + h];
      }
    }
    float mx = fmaxf(fmaxf(p[0][0], p[0][1]), fmaxf(p[0][2], p[0][3]));
#pragma unroll
    for (int ai = 1; ai < 4; ++ai)
      mx = fmaxf(mx, fmaxf(fmaxf(p[ai][0], p[ai][1]), fmaxf(p[ai][2], p[ai][3])));
    mx = fmaxf(mx, __shfl_xor(mx, 16));
    mx = fmaxf(mx, __shfl_xor(mx, 32));

    float sum = 0.f;
#pragma unroll
    for (int ai = 0; ai < 4; ++ai)
#pragma unroll
      for (int r = 0; r < 4; ++r) {
        p[ai][r] = __expf(p[ai][r] - mx);
        sum += p[ai][r];
      }
    sum += __shfl_xor(sum, 16);
    sum += __shfl_xor(sum, 32);
    const float inv = __builtin_amdgcn_rcpf(sum);

    // store via per-wave LDS bounce: 1KB contiguous per instruction
#pragma unroll
    for (int ai = 0; ai < 4; ++ai) {
      const f32x4 o = p[ai] * inv;
      *reinterpret_cast<f32x4*>(lds + pb_addr(pbase, l15, ai * 4 + q)) = o;
    }
#pragma unroll
    for (int i = 0; i < 4; ++i) {
      const int row16 = i * 4 + q;
      const f32x4 v = *reinterpret_cast<const f32x4*>(
          lds + pb_addr(pbase, row16, l15));
      __builtin_nontemporal_store(
          v, reinterpret_cast<f32x4*>(
                 out + obase + (size_t)(bi * 16 + row16) * 64 + l15 * 4));
    }
  }
}

}  // namespace

extern "C" void kernel_launch(void* const* d_in, const int* in_sizes, int n_in,
                              void* d_out, int out_size, void* d_ws, size_t ws_size,
                              hipStream_t stream) {
  const float* x     = (const float*)d_in[0];
  const int*   reidx = (const int*)d_in[1];
  const float* w_in  = (const float*)d_in[2];
  const float* b_in  = (const float*)d_in[3];
  const float* btab  = (const float*)d_in[4];
  const int*   rpidx = (const int*)d_in[5];
  float* out = (float*)d_out;

  const bool use_ws = ws_size >= WS_NEEDED;
  unsigned short* wfrag = (unsigned short*)d_ws;
  float* biasx = (float*)((char*)d_ws + WFRAG_BYTES);

  if (use_ws) {
    prep<<<dim3((WFRAG_ELEMS + BIAS_ELEMS + 255) / 256), dim3(256), 0, stream>>>(
        w_in, btab, rpidx, wfrag, biasx);
    fused_mhaw<true><<<dim3(4096), dim3(256), LDS_TOTAL, stream>>>(
        x, reidx, w_in, b_in, btab, rpidx, wfrag, biasx, out);
  } else {
    fused_mhaw<false><<<dim3(4096), dim3(256), LDS_TOTAL, stream>>>(
        x, reidx, w_in, b_in, btab, rpidx, nullptr, nullptr, out);
  }
}